// Round 5
// baseline (214.351 us; speedup 1.0000x reference)
//
#include <hip/hip_runtime.h>
#include <math.h>

#define NN 50000
#define NE 800000
#define CD 128
#define BSL 32           // bucket slots per node (P(deg>32) ~ 2e-5, overflow path below)
#define OVCAP 65536      // overflow list capacity

typedef __attribute__((ext_vector_type(8))) short short8;
typedef __attribute__((ext_vector_type(4))) float f32x4;

// ---------------- helpers ----------------

__device__ inline unsigned pack2bf(float lo, float hi) {
    unsigned a = __float_as_uint(lo), b = __float_as_uint(hi);
    a = (a + 0x7fffu + ((a >> 16) & 1u)) >> 16;
    b = (b + 0x7fffu + ((b >> 16) & 1u)) & 0xffff0000u;
    return a | b;
}

__device__ inline unsigned short f2bf(float f) {
    unsigned u = __float_as_uint(f);
    return (unsigned short)((u + 0x7fffu + ((u >> 16) & 1u)) >> 16);
}

__device__ inline void fmax2(float* m, unsigned v) {
    m[0] = fmaxf(m[0], __uint_as_float(v << 16));
    m[1] = fmaxf(m[1], __uint_as_float(v & 0xffff0000u));
}

// ---------------- scatter: bucket-CSR build, atomics only ---------------------
// Isolated for attribution: is the ~50us prep cost the atomic path?

__global__ __launch_bounds__(256) void scatter_k(const int* __restrict__ ei,
                                                 int* __restrict__ cnt,
                                                 unsigned short* __restrict__ bkt,
                                                 unsigned* __restrict__ ovl) {
    int e = blockIdx.x * 256 + threadIdx.x;      // grid exact: 3125*256 = NE
    int s = ei[e];
    int d = ei[NE + e];
    int k = atomicAdd(&cnt[d], 1);
    if (k < BSL) {
        bkt[(size_t)d * BSL + k] = (unsigned short)s;
    } else {
        unsigned oi = atomicAdd((unsigned*)&cnt[NN], 1u);
        if (oi < OVCAP) ovl[oi] = ((unsigned)d << 16) | (unsigned)s;
    }
}

// ---------------- cast: x -> bf16 quarter-planes + W transpose ---------------
// xb is stored as 4 planar arrays (one per 32-channel quarter), 3.2 MB each,
// so each XCD's gather working set fits its 4 MB L2.
// plane q, node n, uint u  holds channels q*32 + 2u, q*32 + 2u + 1.

__global__ __launch_bounds__(256) void cast_k(const float* __restrict__ x,
                                              const float* __restrict__ W,
                                              unsigned* __restrict__ xb,
                                              unsigned short* __restrict__ wt) {
    int i = blockIdx.x * 256 + threadIdx.x;      // grid exact: 3125*256 = NN*16
    int n = i >> 4, r = i & 15, q = r >> 2, j = r & 3;
    const float4* xr = (const float4*)(x + (size_t)n * 128 + q * 32 + j * 8);
    float4 a = xr[0], b = xr[1];
    uint4 o;
    o.x = pack2bf(a.x, a.y);
    o.y = pack2bf(a.z, a.w);
    o.z = pack2bf(b.x, b.y);
    o.w = pack2bf(b.z, b.w);
    *(uint4*)(xb + (size_t)q * (NN * 16) + (size_t)n * 16 + j * 4) = o;

    if (i < 2 * CD * CD) {
        int nn = i >> 8, k = i & 255;
        wt[(size_t)nn * 256 + k] = f2bf(W[(size_t)k * 128 + nn]);
    }
}

// ---------------- gather: channel-quartered, XCD-partitioned -----------------
// blockIdx%8 = XCD (measured round-robin); quarter q = (b&7)>>1 so each XCD
// reads exactly one 3.2 MB plane (fits L2). Block = 8 nodes x 32 channels,
// 16 lanes/node, 1 uint (2ch)/lane, 8 source rows in flight on fast path.
// Maxdiff bf16 written into the unused second half of the out row.

__global__ __launch_bounds__(128) void gather_k(const unsigned* __restrict__ xb,
                                                const int* __restrict__ cnt,
                                                const unsigned short* __restrict__ bkt,
                                                const unsigned* __restrict__ ovl,
                                                unsigned* __restrict__ outu) {
    int b = blockIdx.x;                          // 25000 = 6250 tiles x 4 quarters
    int q = (b & 7) >> 1;
    int t = ((b >> 3) << 1) | (b & 1);           // [0, 6250) per quarter, bijective
    int node = t * 8 + (threadIdx.x >> 4);
    int c = threadIdx.x & 15;
    const unsigned* plane = xb + (size_t)q * (NN * 16);

    int cntv = cnt[node];
    int cn = min(cntv, BSL);
    const unsigned short* brow = bkt + (size_t)node * BSL;

    float m[2] = {-INFINITY, -INFINITY};

    for (int base = 0; base < cn; base += 8) {
        uint4 pk = *(const uint4*)(brow + base);
        int s0 = (int)(pk.x & 0xffffu), s1 = (int)(pk.x >> 16);
        int s2 = (int)(pk.y & 0xffffu), s3 = (int)(pk.y >> 16);
        int s4 = (int)(pk.z & 0xffffu), s5 = (int)(pk.z >> 16);
        int s6 = (int)(pk.w & 0xffffu), s7 = (int)(pk.w >> 16);
        if (base + 8 <= cn) {                    // fast path: 8 loads in flight
            fmax2(m, plane[(size_t)s0 * 16 + c]);
            fmax2(m, plane[(size_t)s1 * 16 + c]);
            fmax2(m, plane[(size_t)s2 * 16 + c]);
            fmax2(m, plane[(size_t)s3 * 16 + c]);
            fmax2(m, plane[(size_t)s4 * 16 + c]);
            fmax2(m, plane[(size_t)s5 * 16 + c]);
            fmax2(m, plane[(size_t)s6 * 16 + c]);
            fmax2(m, plane[(size_t)s7 * 16 + c]);
        } else {
            if (base + 0 < cn) fmax2(m, plane[(size_t)s0 * 16 + c]);
            if (base + 1 < cn) fmax2(m, plane[(size_t)s1 * 16 + c]);
            if (base + 2 < cn) fmax2(m, plane[(size_t)s2 * 16 + c]);
            if (base + 3 < cn) fmax2(m, plane[(size_t)s3 * 16 + c]);
            if (base + 4 < cn) fmax2(m, plane[(size_t)s4 * 16 + c]);
            if (base + 5 < cn) fmax2(m, plane[(size_t)s5 * 16 + c]);
            if (base + 6 < cn) fmax2(m, plane[(size_t)s6 * 16 + c]);
            if (base + 7 < cn) fmax2(m, plane[(size_t)s7 * 16 + c]);
        }
    }
    // overflow fallback (degree > BSL): a handful of nodes at most
    if (cntv > BSL) {
        unsigned no = (unsigned)cnt[NN];
        if (no > OVCAP) no = OVCAP;
        for (unsigned i2 = 0; i2 < no; i2++) {
            unsigned u = ovl[i2];
            if ((int)(u >> 16) == node)
                fmax2(m, plane[(size_t)(u & 0xffffu) * 16 + c]);
        }
    }
    unsigned r = 0u;
    if (cntv > 0) {
        unsigned xd = plane[(size_t)node * 16 + c];
        float d0 = m[0] - __uint_as_float(xd << 16);
        float d1 = m[1] - __uint_as_float(xd & 0xffff0000u);
        r = pack2bf(d0, d1);
    }
    outu[(size_t)node * 128 + 64 + q * 16 + c] = r;
}

// ---------------- GEMM: 32-row tiles, A preloaded to regs, then MFMA ---------
// A = [xb planes | amx in out second half]. Barrier after A-preload: C writes
// overwrite the amx region other waves read.

__global__ __launch_bounds__(256) void gemm_k(const unsigned* __restrict__ xb,
                                              const unsigned* __restrict__ amxu,
                                              const short* __restrict__ wt,
                                              const float* __restrict__ bias,
                                              float* __restrict__ out) {
    int t = threadIdx.x;
    int w = t >> 6, lane = t & 63;
    int mm = lane & 15, g = lane >> 4;
    int rt = w & 1, ch = w >> 1;
    int nbase = blockIdx.x * 32;
    int r0 = nbase + rt * 16;
    int row = r0 + mm;
    bool rowok = row < NN;

    uint4 afr[8];
#pragma unroll
    for (int kc = 0; kc < 4; kc++)
        afr[kc] = rowok ? *(const uint4*)(xb + (size_t)kc * (NN * 16) + (size_t)row * 16 + g * 4)
                        : make_uint4(0u, 0u, 0u, 0u);
#pragma unroll
    for (int kc = 4; kc < 8; kc++)
        afr[kc] = rowok ? *(const uint4*)(amxu + (size_t)row * 128 + 64 + (kc - 4) * 16 + g * 4)
                        : make_uint4(0u, 0u, 0u, 0u);

    __syncthreads();   // all A reads (incl. amx region of out) before C writes

    f32x4 acc[4];
#pragma unroll
    for (int ct = 0; ct < 4; ct++) {
        float bv = bias[ch * 64 + ct * 16 + mm];
        acc[ct] = (f32x4){bv, bv, bv, bv};
    }

#pragma unroll
    for (int kc = 0; kc < 8; kc++) {
        short8 a;
        __builtin_memcpy(&a, &afr[kc], 16);
#pragma unroll
        for (int ct = 0; ct < 4; ct++) {
            short8 b = *(const short8*)(wt + (size_t)(ch * 64 + ct * 16 + mm) * 256 + kc * 32 + g * 8);
            acc[ct] = __builtin_amdgcn_mfma_f32_16x16x32_bf16(a, b, acc[ct], 0, 0, 0);
        }
    }

#pragma unroll
    for (int ct = 0; ct < 4; ct++) {
#pragma unroll
        for (int i = 0; i < 4; i++) {
            int rr = r0 + g * 4 + i;
            if (rr < NN) out[(size_t)rr * 128 + ch * 64 + ct * 16 + mm] = acc[ct][i];
        }
    }
}

// ---------------- launch ----------------

extern "C" void kernel_launch(void* const* d_in, const int* in_sizes, int n_in,
                              void* d_out, int out_size, void* d_ws, size_t ws_size,
                              hipStream_t stream) {
    const float* x = (const float*)d_in[0];
    const int* ei = (const int*)d_in[1];     // (2, E): [0..E)=src, [E..2E)=dst
    const float* W = (const float*)d_in[2];  // (256, 128) row-major
    const float* bias = (const float*)d_in[3];
    float* out = (float*)d_out;

    // Workspace layout (ints). Total = 4,131,936 ints = 16.53 MB.
    int* wsi = (int*)d_ws;
    int* cnt = wsi;                                          // 50016 ints (cnt[NN] = overflow count)
    unsigned short* bkt = (unsigned short*)(wsi + 50016);    // NN*32 ush = 800,000 ints (64B-aligned rows)
    unsigned* xb = (unsigned*)(wsi + 850016);                // 4 planes x 800,000 uints (16B-aligned)
    unsigned short* wt = (unsigned short*)(wsi + 4050016);   // 32768 ush = 16384 ints
    unsigned* ovl = (unsigned*)(wsi + 4066400);              // 65536 uints

    hipMemsetAsync(cnt, 0, 50016 * sizeof(int), stream);     // cnt = 0, ovc = 0

    scatter_k<<<NE / 256, 256, 0, stream>>>(ei, cnt, bkt, ovl);
    cast_k<<<NN * 16 / 256, 256, 0, stream>>>(x, W, xb, wt);
    gather_k<<<25000, 128, 0, stream>>>(xb, cnt, bkt, ovl, (unsigned*)out);
    gemm_k<<<(NN + 31) / 32, 256, 0, stream>>>(xb, (const unsigned*)out, (const short*)wt,
                                               bias, out);
}

// Round 6
// 202.105 us; speedup vs baseline: 1.0606x; 1.0606x over previous
//
#include <hip/hip_runtime.h>
#include <math.h>

#define NN 50000
#define NE 800000
#define CD 128
#define BSL 32           // bucket slots per node (P(deg>32) ~ 2e-5, overflow path below)
#define OVCAP 65536      // overflow list capacity
#define SB 125           // edge chunks per dst-slice; grid = 8*SB = 1000 blocks
#define CHK (NE / SB)    // 6400 edges per chunk
#define SLICE (NN / 8)   // 6250 nodes per slice

typedef __attribute__((ext_vector_type(8))) short short8;
typedef __attribute__((ext_vector_type(4))) float f32x4;

// ---------------- helpers ----------------

__device__ inline unsigned pack2bf(float lo, float hi) {
    unsigned a = __float_as_uint(lo), b = __float_as_uint(hi);
    a = (a + 0x7fffu + ((a >> 16) & 1u)) >> 16;
    b = (b + 0x7fffu + ((b >> 16) & 1u)) & 0xffff0000u;
    return a | b;
}

__device__ inline unsigned short f2bf(float f) {
    unsigned u = __float_as_uint(f);
    return (unsigned short)((u + 0x7fffu + ((u >> 16) & 1u)) >> 16);
}

__device__ inline void fmax2(float* m, unsigned v) {
    m[0] = fmaxf(m[0], __uint_as_float(v << 16));
    m[1] = fmaxf(m[1], __uint_as_float(v & 0xffff0000u));
}

// ---------------- scatter: XCD-partitioned bucket-CSR build ------------------
// Block b: dst-slice (b&7) x edge-chunk (b>>3). Under the measured blockIdx%8
// XCD round-robin, each XCD dirties ONLY its 400 KB bucket slice (L2-resident,
// single final writeback) instead of all 8 XCDs dirtying the full 3.2 MB
// (round-5: 47 MB WRITE_SIZE for 1.6 MB payload). dst is scanned 8x from L3
// (cheap); nontemporal loads keep the stream from evicting dirty bucket lines.
// Correctness never depends on the XCD mapping: plain stores to disjoint
// bytes + device-scope atomics.

__global__ __launch_bounds__(256) void scatter_k(const int* __restrict__ ei,
                                                 int* __restrict__ cnt,
                                                 unsigned short* __restrict__ bkt,
                                                 unsigned* __restrict__ ovl) {
    int slice = blockIdx.x & 7;
    int chunk = blockIdx.x >> 3;
    int lo = slice * SLICE;
    int e0 = chunk * CHK;
    const int* dsts = ei + NE;

    for (int e = e0 + threadIdx.x; e < e0 + CHK; e += 256) {
        int d = __builtin_nontemporal_load(dsts + e);
        if ((unsigned)(d - lo) < (unsigned)SLICE) {
            int s = __builtin_nontemporal_load(ei + e);
            int k = atomicAdd(&cnt[d], 1);
            if (k < BSL) {
                bkt[(size_t)d * BSL + k] = (unsigned short)s;
            } else {
                unsigned oi = atomicAdd((unsigned*)&cnt[NN], 1u);
                if (oi < OVCAP) ovl[oi] = ((unsigned)d << 16) | (unsigned)s;
            }
        }
    }
}

// ---------------- cast: x -> bf16 quarter-planes + W transpose ---------------
// xb is stored as 4 planar arrays (one per 32-channel quarter), 3.2 MB each,
// so each XCD's gather working set fits its 4 MB L2.
// plane q, node n, uint u  holds channels q*32 + 2u, q*32 + 2u + 1.

__global__ __launch_bounds__(256) void cast_k(const float* __restrict__ x,
                                              const float* __restrict__ W,
                                              unsigned* __restrict__ xb,
                                              unsigned short* __restrict__ wt) {
    int i = blockIdx.x * 256 + threadIdx.x;      // grid exact: 3125*256 = NN*16
    int n = i >> 4, r = i & 15, q = r >> 2, j = r & 3;
    const float4* xr = (const float4*)(x + (size_t)n * 128 + q * 32 + j * 8);
    float4 a = xr[0], b = xr[1];
    uint4 o;
    o.x = pack2bf(a.x, a.y);
    o.y = pack2bf(a.z, a.w);
    o.z = pack2bf(b.x, b.y);
    o.w = pack2bf(b.z, b.w);
    *(uint4*)(xb + (size_t)q * (NN * 16) + (size_t)n * 16 + j * 4) = o;

    if (i < 2 * CD * CD) {
        int nn = i >> 8, k = i & 255;
        wt[(size_t)nn * 256 + k] = f2bf(W[(size_t)k * 128 + nn]);
    }
}

// ---------------- gather: channel-quartered, XCD-partitioned -----------------
// blockIdx%8 = XCD (measured round-robin); quarter q = (b&7)>>1 so each XCD
// reads exactly one 3.2 MB plane (fits L2). Block = 8 nodes x 32 channels,
// 16 lanes/node, 1 uint (2ch)/lane, 8 source rows in flight on fast path.
// Maxdiff bf16 written into the unused second half of the out row.

__global__ __launch_bounds__(128) void gather_k(const unsigned* __restrict__ xb,
                                                const int* __restrict__ cnt,
                                                const unsigned short* __restrict__ bkt,
                                                const unsigned* __restrict__ ovl,
                                                unsigned* __restrict__ outu) {
    int b = blockIdx.x;                          // 25000 = 6250 tiles x 4 quarters
    int q = (b & 7) >> 1;
    int t = ((b >> 3) << 1) | (b & 1);           // [0, 6250) per quarter, bijective
    int node = t * 8 + (threadIdx.x >> 4);
    int c = threadIdx.x & 15;
    const unsigned* plane = xb + (size_t)q * (NN * 16);

    int cntv = cnt[node];
    int cn = min(cntv, BSL);
    const unsigned short* brow = bkt + (size_t)node * BSL;

    float m[2] = {-INFINITY, -INFINITY};

    for (int base = 0; base < cn; base += 8) {
        uint4 pk = *(const uint4*)(brow + base);
        int s0 = (int)(pk.x & 0xffffu), s1 = (int)(pk.x >> 16);
        int s2 = (int)(pk.y & 0xffffu), s3 = (int)(pk.y >> 16);
        int s4 = (int)(pk.z & 0xffffu), s5 = (int)(pk.z >> 16);
        int s6 = (int)(pk.w & 0xffffu), s7 = (int)(pk.w >> 16);
        if (base + 8 <= cn) {                    // fast path: 8 loads in flight
            fmax2(m, plane[(size_t)s0 * 16 + c]);
            fmax2(m, plane[(size_t)s1 * 16 + c]);
            fmax2(m, plane[(size_t)s2 * 16 + c]);
            fmax2(m, plane[(size_t)s3 * 16 + c]);
            fmax2(m, plane[(size_t)s4 * 16 + c]);
            fmax2(m, plane[(size_t)s5 * 16 + c]);
            fmax2(m, plane[(size_t)s6 * 16 + c]);
            fmax2(m, plane[(size_t)s7 * 16 + c]);
        } else {
            if (base + 0 < cn) fmax2(m, plane[(size_t)s0 * 16 + c]);
            if (base + 1 < cn) fmax2(m, plane[(size_t)s1 * 16 + c]);
            if (base + 2 < cn) fmax2(m, plane[(size_t)s2 * 16 + c]);
            if (base + 3 < cn) fmax2(m, plane[(size_t)s3 * 16 + c]);
            if (base + 4 < cn) fmax2(m, plane[(size_t)s4 * 16 + c]);
            if (base + 5 < cn) fmax2(m, plane[(size_t)s5 * 16 + c]);
            if (base + 6 < cn) fmax2(m, plane[(size_t)s6 * 16 + c]);
            if (base + 7 < cn) fmax2(m, plane[(size_t)s7 * 16 + c]);
        }
    }
    // overflow fallback (degree > BSL): a handful of nodes at most
    if (cntv > BSL) {
        unsigned no = (unsigned)cnt[NN];
        if (no > OVCAP) no = OVCAP;
        for (unsigned i2 = 0; i2 < no; i2++) {
            unsigned u = ovl[i2];
            if ((int)(u >> 16) == node)
                fmax2(m, plane[(size_t)(u & 0xffffu) * 16 + c]);
        }
    }
    unsigned r = 0u;
    if (cntv > 0) {
        unsigned xd = plane[(size_t)node * 16 + c];
        float d0 = m[0] - __uint_as_float(xd << 16);
        float d1 = m[1] - __uint_as_float(xd & 0xffff0000u);
        r = pack2bf(d0, d1);
    }
    outu[(size_t)node * 128 + 64 + q * 16 + c] = r;
}

// ---------------- GEMM: 32-row tiles, A preloaded to regs, then MFMA ---------
// A = [xb planes | amx in out second half]. Barrier after A-preload: C writes
// overwrite the amx region other waves read.

__global__ __launch_bounds__(256) void gemm_k(const unsigned* __restrict__ xb,
                                              const unsigned* __restrict__ amxu,
                                              const short* __restrict__ wt,
                                              const float* __restrict__ bias,
                                              float* __restrict__ out) {
    int t = threadIdx.x;
    int w = t >> 6, lane = t & 63;
    int mm = lane & 15, g = lane >> 4;
    int rt = w & 1, ch = w >> 1;
    int nbase = blockIdx.x * 32;
    int r0 = nbase + rt * 16;
    int row = r0 + mm;
    bool rowok = row < NN;

    uint4 afr[8];
#pragma unroll
    for (int kc = 0; kc < 4; kc++)
        afr[kc] = rowok ? *(const uint4*)(xb + (size_t)kc * (NN * 16) + (size_t)row * 16 + g * 4)
                        : make_uint4(0u, 0u, 0u, 0u);
#pragma unroll
    for (int kc = 4; kc < 8; kc++)
        afr[kc] = rowok ? *(const uint4*)(amxu + (size_t)row * 128 + 64 + (kc - 4) * 16 + g * 4)
                        : make_uint4(0u, 0u, 0u, 0u);

    __syncthreads();   // all A reads (incl. amx region of out) before C writes

    f32x4 acc[4];
#pragma unroll
    for (int ct = 0; ct < 4; ct++) {
        float bv = bias[ch * 64 + ct * 16 + mm];
        acc[ct] = (f32x4){bv, bv, bv, bv};
    }

#pragma unroll
    for (int kc = 0; kc < 8; kc++) {
        short8 a;
        __builtin_memcpy(&a, &afr[kc], 16);
#pragma unroll
        for (int ct = 0; ct < 4; ct++) {
            short8 b = *(const short8*)(wt + (size_t)(ch * 64 + ct * 16 + mm) * 256 + kc * 32 + g * 8);
            acc[ct] = __builtin_amdgcn_mfma_f32_16x16x32_bf16(a, b, acc[ct], 0, 0, 0);
        }
    }

#pragma unroll
    for (int ct = 0; ct < 4; ct++) {
#pragma unroll
        for (int i = 0; i < 4; i++) {
            int rr = r0 + g * 4 + i;
            if (rr < NN) out[(size_t)rr * 128 + ch * 64 + ct * 16 + mm] = acc[ct][i];
        }
    }
}

// ---------------- launch ----------------

extern "C" void kernel_launch(void* const* d_in, const int* in_sizes, int n_in,
                              void* d_out, int out_size, void* d_ws, size_t ws_size,
                              hipStream_t stream) {
    const float* x = (const float*)d_in[0];
    const int* ei = (const int*)d_in[1];     // (2, E): [0..E)=src, [E..2E)=dst
    const float* W = (const float*)d_in[2];  // (256, 128) row-major
    const float* bias = (const float*)d_in[3];
    float* out = (float*)d_out;

    // Workspace layout (ints). Total = 4,131,936 ints = 16.53 MB.
    int* wsi = (int*)d_ws;
    int* cnt = wsi;                                          // 50016 ints (cnt[NN] = overflow count)
    unsigned short* bkt = (unsigned short*)(wsi + 50016);    // NN*32 ush = 800,000 ints (64B-aligned rows)
    unsigned* xb = (unsigned*)(wsi + 850016);                // 4 planes x 800,000 uints (16B-aligned)
    unsigned short* wt = (unsigned short*)(wsi + 4050016);   // 32768 ush = 16384 ints
    unsigned* ovl = (unsigned*)(wsi + 4066400);              // 65536 uints

    hipMemsetAsync(cnt, 0, 50016 * sizeof(int), stream);     // cnt = 0, ovc = 0

    scatter_k<<<8 * SB, 256, 0, stream>>>(ei, cnt, bkt, ovl);
    cast_k<<<NN * 16 / 256, 256, 0, stream>>>(x, W, xb, wt);
    gather_k<<<25000, 128, 0, stream>>>(xb, cnt, bkt, ovl, (unsigned*)out);
    gemm_k<<<(NN + 31) / 32, 256, 0, stream>>>(xb, (const unsigned*)out, (const short*)wt,
                                               bias, out);
}

// Round 8
// 193.521 us; speedup vs baseline: 1.1076x; 1.0444x over previous
//
#include <hip/hip_runtime.h>
#include <math.h>

#define NN 50000
#define NE 800000
#define CD 128
#define BSL 32           // bucket slots per node (P(deg>32) ~ 2e-5, overflow path below)
#define OVCAP 65536      // overflow list capacity
#define SB 125           // edge chunks per dst-slice; prep grid = 8*SB = 1000 blocks
#define CHK (NE / SB)    // 6400 edges per chunk
#define SLICE (NN / 8)   // 6250 nodes per slice
#define PGRID (8 * SB * 256)

typedef __attribute__((ext_vector_type(8))) short short8;
typedef __attribute__((ext_vector_type(4))) float f32x4;
typedef __attribute__((ext_vector_type(4))) unsigned uint4v;   // clang vector: valid for nontemporal builtins

// ---------------- helpers ----------------

__device__ inline unsigned pack2bf(float lo, float hi) {
    unsigned a = __float_as_uint(lo), b = __float_as_uint(hi);
    a = (a + 0x7fffu + ((a >> 16) & 1u)) >> 16;
    b = (b + 0x7fffu + ((b >> 16) & 1u)) & 0xffff0000u;
    return a | b;
}

__device__ inline unsigned short f2bf(float f) {
    unsigned u = __float_as_uint(f);
    return (unsigned short)((u + 0x7fffu + ((u >> 16) & 1u)) >> 16);
}

__device__ inline void fmax8(float* m, uint4 v) {
    m[0] = fmaxf(m[0], __uint_as_float(v.x << 16));
    m[1] = fmaxf(m[1], __uint_as_float(v.x & 0xffff0000u));
    m[2] = fmaxf(m[2], __uint_as_float(v.y << 16));
    m[3] = fmaxf(m[3], __uint_as_float(v.y & 0xffff0000u));
    m[4] = fmaxf(m[4], __uint_as_float(v.z << 16));
    m[5] = fmaxf(m[5], __uint_as_float(v.z & 0xffff0000u));
    m[6] = fmaxf(m[6], __uint_as_float(v.w << 16));
    m[7] = fmaxf(m[7], __uint_as_float(v.w & 0xffff0000u));
}

// ---------------- prep: XCD-partitioned scatter + staggered bf16 casts -------
// Scatter: block b owns dst-slice (b&7) x edge-chunk (b>>3); under the measured
// blockIdx%8 XCD round-robin each XCD dirties only its 400 KB bucket slice
// (round-5's 47 MB write-amplification -> ~5 MB). dst scanned 8x from L3.
// Cast: grid-strided, parity-staggered with scatter (round-3: overlaps fully
// under atomic latency); nontemporal so the stream doesn't evict bucket lines.
// Correctness never depends on the XCD mapping: disjoint-byte plain stores +
// device-scope atomics.

__global__ __launch_bounds__(256) void prep_k(const int* __restrict__ ei,
                                              const float* __restrict__ x,
                                              const float* __restrict__ W,
                                              int* __restrict__ cnt,
                                              unsigned short* __restrict__ bkt,
                                              unsigned* __restrict__ ovl,
                                              unsigned* __restrict__ xb,
                                              unsigned short* __restrict__ wt) {
    int tid0 = blockIdx.x * 256 + threadIdx.x;
    int slice = blockIdx.x & 7;
    int chunk = blockIdx.x >> 3;
    int phase = chunk & 1;

    for (int p = 0; p < 2; p++) {
        if ((p ^ phase) == 0) {
            // scatter my slice-chunk
            int lo = slice * SLICE;
            int e0 = chunk * CHK;
            const int* dsts = ei + NE;
            for (int e = e0 + threadIdx.x; e < e0 + CHK; e += 256) {
                int d = __builtin_nontemporal_load(dsts + e);
                if ((unsigned)(d - lo) < (unsigned)SLICE) {
                    int s = __builtin_nontemporal_load(ei + e);
                    int k = atomicAdd(&cnt[d], 1);
                    if (k < BSL) {
                        bkt[(size_t)d * BSL + k] = (unsigned short)s;
                    } else {
                        unsigned oi = atomicAdd((unsigned*)&cnt[NN], 1u);
                        if (oi < OVCAP) ovl[oi] = ((unsigned)d << 16) | (unsigned)s;
                    }
                }
            }
        } else {
            // x -> bf16 quarter-planes: plane q, node n, uint u holds
            // channels q*32 + 2u, q*32 + 2u + 1. 3.2 MB per plane.
            for (int i = tid0; i < NN * 16; i += PGRID) {
                int n = i >> 4, r = i & 15, q = r >> 2, j = r & 3;
                const float* xr = x + (size_t)n * 128 + q * 32 + j * 8;
                float4 a, b;
                a.x = __builtin_nontemporal_load(xr + 0);
                a.y = __builtin_nontemporal_load(xr + 1);
                a.z = __builtin_nontemporal_load(xr + 2);
                a.w = __builtin_nontemporal_load(xr + 3);
                b.x = __builtin_nontemporal_load(xr + 4);
                b.y = __builtin_nontemporal_load(xr + 5);
                b.z = __builtin_nontemporal_load(xr + 6);
                b.w = __builtin_nontemporal_load(xr + 7);
                uint4v o;
                o.x = pack2bf(a.x, a.y);
                o.y = pack2bf(a.z, a.w);
                o.z = pack2bf(b.x, b.y);
                o.w = pack2bf(b.z, b.w);
                __builtin_nontemporal_store(o, (uint4v*)(xb + (size_t)q * (NN * 16) + (size_t)n * 16 + j * 4));
            }
        }
    }
    // W -> transposed bf16 wt[n][k] (tiny)
    for (int i = tid0; i < 2 * CD * CD; i += PGRID) {
        int n = i >> 8, k = i & 255;
        wt[(size_t)n * 256 + k] = f2bf(W[(size_t)k * 128 + n]);
    }
}

// ---------------- gather: channel-quartered, XCD-partitioned, wide loads -----
// Quarter q = (b&7)>>1 so each XCD reads exactly one 3.2 MB plane (fits L2;
// round-6: FETCH 85->25 MB). Round-6 lesson: 4 B/lane loads made it
// instruction/latency-bound (VALUBusy 38%, 590 GB/s). Now 4 lanes/node x
// uint4 (16 B/lane, 1 KB/wave-instr): 4x fewer VMEM instrs, 4x MLP.
// Block = 32 nodes x 4 lanes; 8 source rows in flight on the fast path.
// Maxdiff bf16 written into the unused second half of the out row.

__global__ __launch_bounds__(128) void gather_k(const unsigned* __restrict__ xb,
                                                const int* __restrict__ cnt,
                                                const unsigned short* __restrict__ bkt,
                                                const unsigned* __restrict__ ovl,
                                                unsigned* __restrict__ outu) {
    int b = blockIdx.x;                          // 6256 = 8 * 782
    int q = (b & 7) >> 1;
    int t = ((b >> 3) << 1) | (b & 1);           // [0, 1564), bijective per quarter
    int node = t * 32 + (threadIdx.x >> 2);
    int j = threadIdx.x & 3;                     // lane's uint4 within the plane row
    const unsigned* plane = xb + (size_t)q * (NN * 16);

    int cntv = (node < NN) ? cnt[node] : 0;
    int cn = min(cntv, BSL);
    const unsigned short* brow = bkt + (size_t)node * BSL;

    float m[8];
#pragma unroll
    for (int i = 0; i < 8; i++) m[i] = -INFINITY;

    for (int base = 0; base < cn; base += 8) {
        uint4 pk = *(const uint4*)(brow + base);
        int s0 = (int)(pk.x & 0xffffu), s1 = (int)(pk.x >> 16);
        int s2 = (int)(pk.y & 0xffffu), s3 = (int)(pk.y >> 16);
        int s4 = (int)(pk.z & 0xffffu), s5 = (int)(pk.z >> 16);
        int s6 = (int)(pk.w & 0xffffu), s7 = (int)(pk.w >> 16);
        if (base + 8 <= cn) {                    // fast path: 8 loads in flight
            fmax8(m, *(const uint4*)(plane + (size_t)s0 * 16 + j * 4));
            fmax8(m, *(const uint4*)(plane + (size_t)s1 * 16 + j * 4));
            fmax8(m, *(const uint4*)(plane + (size_t)s2 * 16 + j * 4));
            fmax8(m, *(const uint4*)(plane + (size_t)s3 * 16 + j * 4));
            fmax8(m, *(const uint4*)(plane + (size_t)s4 * 16 + j * 4));
            fmax8(m, *(const uint4*)(plane + (size_t)s5 * 16 + j * 4));
            fmax8(m, *(const uint4*)(plane + (size_t)s6 * 16 + j * 4));
            fmax8(m, *(const uint4*)(plane + (size_t)s7 * 16 + j * 4));
        } else {
            if (base + 0 < cn) fmax8(m, *(const uint4*)(plane + (size_t)s0 * 16 + j * 4));
            if (base + 1 < cn) fmax8(m, *(const uint4*)(plane + (size_t)s1 * 16 + j * 4));
            if (base + 2 < cn) fmax8(m, *(const uint4*)(plane + (size_t)s2 * 16 + j * 4));
            if (base + 3 < cn) fmax8(m, *(const uint4*)(plane + (size_t)s3 * 16 + j * 4));
            if (base + 4 < cn) fmax8(m, *(const uint4*)(plane + (size_t)s4 * 16 + j * 4));
            if (base + 5 < cn) fmax8(m, *(const uint4*)(plane + (size_t)s5 * 16 + j * 4));
            if (base + 6 < cn) fmax8(m, *(const uint4*)(plane + (size_t)s6 * 16 + j * 4));
            if (base + 7 < cn) fmax8(m, *(const uint4*)(plane + (size_t)s7 * 16 + j * 4));
        }
    }
    // overflow fallback (degree > BSL): a handful of nodes at most
    if (cntv > BSL) {
        unsigned no = (unsigned)cnt[NN];
        if (no > OVCAP) no = OVCAP;
        for (unsigned i2 = 0; i2 < no; i2++) {
            unsigned u = ovl[i2];
            if ((int)(u >> 16) == node)
                fmax8(m, *(const uint4*)(plane + (size_t)(u & 0xffffu) * 16 + j * 4));
        }
    }
    uint4 r = make_uint4(0u, 0u, 0u, 0u);
    if (cntv > 0) {
        uint4 xd = *(const uint4*)(plane + (size_t)node * 16 + j * 4);
        float d0 = m[0] - __uint_as_float(xd.x << 16);
        float d1 = m[1] - __uint_as_float(xd.x & 0xffff0000u);
        float d2 = m[2] - __uint_as_float(xd.y << 16);
        float d3 = m[3] - __uint_as_float(xd.y & 0xffff0000u);
        float d4 = m[4] - __uint_as_float(xd.z << 16);
        float d5 = m[5] - __uint_as_float(xd.z & 0xffff0000u);
        float d6 = m[6] - __uint_as_float(xd.w << 16);
        float d7 = m[7] - __uint_as_float(xd.w & 0xffff0000u);
        r.x = pack2bf(d0, d1);
        r.y = pack2bf(d2, d3);
        r.z = pack2bf(d4, d5);
        r.w = pack2bf(d6, d7);
    }
    if (node < NN)
        *(uint4*)(outu + (size_t)node * 128 + 64 + q * 16 + j * 4) = r;
}

// ---------------- GEMM: 32-row tiles, A preloaded to regs, then MFMA ---------
// A = [xb planes | amx in out second half]. Barrier after A-preload: C writes
// overwrite the amx region other waves read.

__global__ __launch_bounds__(256) void gemm_k(const unsigned* __restrict__ xb,
                                              const unsigned* __restrict__ amxu,
                                              const short* __restrict__ wt,
                                              const float* __restrict__ bias,
                                              float* __restrict__ out) {
    int t = threadIdx.x;
    int w = t >> 6, lane = t & 63;
    int mm = lane & 15, g = lane >> 4;
    int rt = w & 1, ch = w >> 1;
    int nbase = blockIdx.x * 32;
    int r0 = nbase + rt * 16;
    int row = r0 + mm;
    bool rowok = row < NN;

    uint4 afr[8];
#pragma unroll
    for (int kc = 0; kc < 4; kc++)
        afr[kc] = rowok ? *(const uint4*)(xb + (size_t)kc * (NN * 16) + (size_t)row * 16 + g * 4)
                        : make_uint4(0u, 0u, 0u, 0u);
#pragma unroll
    for (int kc = 4; kc < 8; kc++)
        afr[kc] = rowok ? *(const uint4*)(amxu + (size_t)row * 128 + 64 + (kc - 4) * 16 + g * 4)
                        : make_uint4(0u, 0u, 0u, 0u);

    __syncthreads();   // all A reads (incl. amx region of out) before C writes

    f32x4 acc[4];
#pragma unroll
    for (int ct = 0; ct < 4; ct++) {
        float bv = bias[ch * 64 + ct * 16 + mm];
        acc[ct] = (f32x4){bv, bv, bv, bv};
    }

#pragma unroll
    for (int kc = 0; kc < 8; kc++) {
        short8 a;
        __builtin_memcpy(&a, &afr[kc], 16);
#pragma unroll
        for (int ct = 0; ct < 4; ct++) {
            short8 b = *(const short8*)(wt + (size_t)(ch * 64 + ct * 16 + mm) * 256 + kc * 32 + g * 8);
            acc[ct] = __builtin_amdgcn_mfma_f32_16x16x32_bf16(a, b, acc[ct], 0, 0, 0);
        }
    }

#pragma unroll
    for (int ct = 0; ct < 4; ct++) {
#pragma unroll
        for (int i = 0; i < 4; i++) {
            int rr = r0 + g * 4 + i;
            if (rr < NN) out[(size_t)rr * 128 + ch * 64 + ct * 16 + mm] = acc[ct][i];
        }
    }
}

// ---------------- launch ----------------

extern "C" void kernel_launch(void* const* d_in, const int* in_sizes, int n_in,
                              void* d_out, int out_size, void* d_ws, size_t ws_size,
                              hipStream_t stream) {
    const float* x = (const float*)d_in[0];
    const int* ei = (const int*)d_in[1];     // (2, E): [0..E)=src, [E..2E)=dst
    const float* W = (const float*)d_in[2];  // (256, 128) row-major
    const float* bias = (const float*)d_in[3];
    float* out = (float*)d_out;

    // Workspace layout (ints). Total = 4,131,936 ints = 16.53 MB.
    int* wsi = (int*)d_ws;
    int* cnt = wsi;                                          // 50016 ints (cnt[NN] = overflow count)
    unsigned short* bkt = (unsigned short*)(wsi + 50016);    // NN*32 ush = 800,000 ints (64B-aligned rows)
    unsigned* xb = (unsigned*)(wsi + 850016);                // 4 planes x 800,000 uints (16B-aligned)
    unsigned short* wt = (unsigned short*)(wsi + 4050016);   // 32768 ush = 16384 ints
    unsigned* ovl = (unsigned*)(wsi + 4066400);              // 65536 uints

    (void)hipMemsetAsync(cnt, 0, 50016 * sizeof(int), stream);   // cnt = 0, ovc = 0

    prep_k<<<8 * SB, 256, 0, stream>>>(ei, x, W, cnt, bkt, ovl, xb, wt);
    gather_k<<<6256, 128, 0, stream>>>(xb, cnt, bkt, ovl, (unsigned*)out);
    gemm_k<<<(NN + 31) / 32, 256, 0, stream>>>(xb, (const unsigned*)out, (const short*)wt,
                                               bias, out);
}

// Round 9
// 189.168 us; speedup vs baseline: 1.1331x; 1.0230x over previous
//
#include <hip/hip_runtime.h>
#include <math.h>

#define NN 50000
#define NE 800000
#define CD 128
#define BSL 32           // bucket slots per node (P(deg>32) ~ 2e-5, overflow path below)
#define OVCAP 65536      // overflow list capacity
#define SB 250           // edge chunks per dst-slice; prep grid = 8*SB = 2000 blocks
#define CHK (NE / SB)    // 3200 edges per chunk
#define SLICE (NN / 8)   // 6250 nodes per slice
#define PGRID (8 * SB * 256)
#define CPAD 16          // cnt stride in ints: one dst per 64B line (atomic line-serialization probe)

typedef __attribute__((ext_vector_type(8))) short short8;
typedef __attribute__((ext_vector_type(4))) float f32x4;
typedef __attribute__((ext_vector_type(4))) unsigned uint4v;   // clang vector: valid for nontemporal builtins

// ---------------- helpers ----------------

__device__ inline unsigned pack2bf(float lo, float hi) {
    unsigned a = __float_as_uint(lo), b = __float_as_uint(hi);
    a = (a + 0x7fffu + ((a >> 16) & 1u)) >> 16;
    b = (b + 0x7fffu + ((b >> 16) & 1u)) & 0xffff0000u;
    return a | b;
}

__device__ inline unsigned short f2bf(float f) {
    unsigned u = __float_as_uint(f);
    return (unsigned short)((u + 0x7fffu + ((u >> 16) & 1u)) >> 16);
}

__device__ inline void fmax8(float* m, uint4 v) {
    m[0] = fmaxf(m[0], __uint_as_float(v.x << 16));
    m[1] = fmaxf(m[1], __uint_as_float(v.x & 0xffff0000u));
    m[2] = fmaxf(m[2], __uint_as_float(v.y << 16));
    m[3] = fmaxf(m[3], __uint_as_float(v.y & 0xffff0000u));
    m[4] = fmaxf(m[4], __uint_as_float(v.z << 16));
    m[5] = fmaxf(m[5], __uint_as_float(v.z & 0xffff0000u));
    m[6] = fmaxf(m[6], __uint_as_float(v.w << 16));
    m[7] = fmaxf(m[7], __uint_as_float(v.w & 0xffff0000u));
}

__device__ inline void scat1(int d, int s, int* cnt, unsigned short* bkt, unsigned* ovl) {
    int k = atomicAdd(&cnt[(size_t)d * CPAD], 1);
    if (k < BSL) {
        bkt[(size_t)d * BSL + k] = (unsigned short)s;
    } else {
        unsigned oi = atomicAdd((unsigned*)&cnt[(size_t)NN * CPAD], 1u);
        if (oi < OVCAP) ovl[oi] = ((unsigned)d << 16) | (unsigned)s;
    }
}

// ---------------- prep: XCD-partitioned scatter + staggered bf16 casts -------
// Scatter: block b owns dst-slice (b&7) x edge-chunk (b>>3); under the measured
// blockIdx%8 XCD round-robin each XCD dirties only its bucket slice. cnt is
// padded to 64 B per dst: round-8 showed prep at 50us with ALL pipes idle ->
// hypothesis is line-granular serialization at the device atomic unit
// (16 dst/line x 16 ops/dst = 256 chained RMW per line when packed).
// dst scanned 8x from L3 via int4 loads (4 edges/lane-load).
// Correctness never depends on the XCD mapping: disjoint-byte plain stores +
// device-scope atomics.

__global__ __launch_bounds__(256) void prep_k(const int* __restrict__ ei,
                                              const float* __restrict__ x,
                                              const float* __restrict__ W,
                                              int* __restrict__ cnt,
                                              unsigned short* __restrict__ bkt,
                                              unsigned* __restrict__ ovl,
                                              unsigned* __restrict__ xb,
                                              unsigned short* __restrict__ wt) {
    int tid0 = blockIdx.x * 256 + threadIdx.x;
    int slice = blockIdx.x & 7;
    int chunk = blockIdx.x >> 3;
    int phase = chunk & 1;

    for (int p = 0; p < 2; p++) {
        if ((p ^ phase) == 0) {
            // scatter my slice-chunk: int4 dst scan, 4 edges per lane-load
            int lo = slice * SLICE;
            const int4* d4 = (const int4*)(ei + NE + chunk * CHK);
            const int* srcs = ei + chunk * CHK;
            for (int i = threadIdx.x; i < CHK / 4; i += 256) {
                int4 dv = d4[i];
                int e = i * 4;
                if ((unsigned)(dv.x - lo) < (unsigned)SLICE) scat1(dv.x, srcs[e + 0], cnt, bkt, ovl);
                if ((unsigned)(dv.y - lo) < (unsigned)SLICE) scat1(dv.y, srcs[e + 1], cnt, bkt, ovl);
                if ((unsigned)(dv.z - lo) < (unsigned)SLICE) scat1(dv.z, srcs[e + 2], cnt, bkt, ovl);
                if ((unsigned)(dv.w - lo) < (unsigned)SLICE) scat1(dv.w, srcs[e + 3], cnt, bkt, ovl);
            }
        } else {
            // x -> bf16 quarter-planes: plane q, node n, uint u holds
            // channels q*32 + 2u, q*32 + 2u + 1. 3.2 MB per plane.
            for (int i = tid0; i < NN * 16; i += PGRID) {
                int n = i >> 4, r = i & 15, q = r >> 2, j = r & 3;
                const float* xr = x + (size_t)n * 128 + q * 32 + j * 8;
                float4 a, b;
                a.x = __builtin_nontemporal_load(xr + 0);
                a.y = __builtin_nontemporal_load(xr + 1);
                a.z = __builtin_nontemporal_load(xr + 2);
                a.w = __builtin_nontemporal_load(xr + 3);
                b.x = __builtin_nontemporal_load(xr + 4);
                b.y = __builtin_nontemporal_load(xr + 5);
                b.z = __builtin_nontemporal_load(xr + 6);
                b.w = __builtin_nontemporal_load(xr + 7);
                uint4v o;
                o.x = pack2bf(a.x, a.y);
                o.y = pack2bf(a.z, a.w);
                o.z = pack2bf(b.x, b.y);
                o.w = pack2bf(b.z, b.w);
                __builtin_nontemporal_store(o, (uint4v*)(xb + (size_t)q * (NN * 16) + (size_t)n * 16 + j * 4));
            }
        }
    }
    // W -> transposed bf16 wt[n][k] (tiny)
    for (int i = tid0; i < 2 * CD * CD; i += PGRID) {
        int n = i >> 8, k = i & 255;
        wt[(size_t)n * 256 + k] = f2bf(W[(size_t)k * 128 + n]);
    }
}

// ---------------- gather: channel-quartered, XCD-partitioned, wide loads -----
// Quarter q = (b&7)>>1 so each XCD reads exactly one 3.2 MB plane (fits L2).
// 4 lanes/node x uint4 (16 B/lane); 8 source rows in flight on the fast path.
// Maxdiff bf16 written into the unused second half of the out row.

__global__ __launch_bounds__(128) void gather_k(const unsigned* __restrict__ xb,
                                                const int* __restrict__ cnt,
                                                const unsigned short* __restrict__ bkt,
                                                const unsigned* __restrict__ ovl,
                                                unsigned* __restrict__ outu) {
    int b = blockIdx.x;                          // 6256 = 8 * 782
    int q = (b & 7) >> 1;
    int t = ((b >> 3) << 1) | (b & 1);           // [0, 1564), bijective per quarter
    int node = t * 32 + (threadIdx.x >> 2);
    int j = threadIdx.x & 3;                     // lane's uint4 within the plane row
    const unsigned* plane = xb + (size_t)q * (NN * 16);

    int cntv = (node < NN) ? cnt[(size_t)node * CPAD] : 0;
    int cn = min(cntv, BSL);
    const unsigned short* brow = bkt + (size_t)node * BSL;

    float m[8];
#pragma unroll
    for (int i = 0; i < 8; i++) m[i] = -INFINITY;

    for (int base = 0; base < cn; base += 8) {
        uint4 pk = *(const uint4*)(brow + base);
        int s0 = (int)(pk.x & 0xffffu), s1 = (int)(pk.x >> 16);
        int s2 = (int)(pk.y & 0xffffu), s3 = (int)(pk.y >> 16);
        int s4 = (int)(pk.z & 0xffffu), s5 = (int)(pk.z >> 16);
        int s6 = (int)(pk.w & 0xffffu), s7 = (int)(pk.w >> 16);
        if (base + 8 <= cn) {                    // fast path: 8 loads in flight
            fmax8(m, *(const uint4*)(plane + (size_t)s0 * 16 + j * 4));
            fmax8(m, *(const uint4*)(plane + (size_t)s1 * 16 + j * 4));
            fmax8(m, *(const uint4*)(plane + (size_t)s2 * 16 + j * 4));
            fmax8(m, *(const uint4*)(plane + (size_t)s3 * 16 + j * 4));
            fmax8(m, *(const uint4*)(plane + (size_t)s4 * 16 + j * 4));
            fmax8(m, *(const uint4*)(plane + (size_t)s5 * 16 + j * 4));
            fmax8(m, *(const uint4*)(plane + (size_t)s6 * 16 + j * 4));
            fmax8(m, *(const uint4*)(plane + (size_t)s7 * 16 + j * 4));
        } else {
            if (base + 0 < cn) fmax8(m, *(const uint4*)(plane + (size_t)s0 * 16 + j * 4));
            if (base + 1 < cn) fmax8(m, *(const uint4*)(plane + (size_t)s1 * 16 + j * 4));
            if (base + 2 < cn) fmax8(m, *(const uint4*)(plane + (size_t)s2 * 16 + j * 4));
            if (base + 3 < cn) fmax8(m, *(const uint4*)(plane + (size_t)s3 * 16 + j * 4));
            if (base + 4 < cn) fmax8(m, *(const uint4*)(plane + (size_t)s4 * 16 + j * 4));
            if (base + 5 < cn) fmax8(m, *(const uint4*)(plane + (size_t)s5 * 16 + j * 4));
            if (base + 6 < cn) fmax8(m, *(const uint4*)(plane + (size_t)s6 * 16 + j * 4));
            if (base + 7 < cn) fmax8(m, *(const uint4*)(plane + (size_t)s7 * 16 + j * 4));
        }
    }
    // overflow fallback (degree > BSL): a handful of nodes at most
    if (cntv > BSL) {
        unsigned no = (unsigned)cnt[(size_t)NN * CPAD];
        if (no > OVCAP) no = OVCAP;
        for (unsigned i2 = 0; i2 < no; i2++) {
            unsigned u = ovl[i2];
            if ((int)(u >> 16) == node)
                fmax8(m, *(const uint4*)(plane + (size_t)(u & 0xffffu) * 16 + j * 4));
        }
    }
    uint4 r = make_uint4(0u, 0u, 0u, 0u);
    if (cntv > 0) {
        uint4 xd = *(const uint4*)(plane + (size_t)node * 16 + j * 4);
        float d0 = m[0] - __uint_as_float(xd.x << 16);
        float d1 = m[1] - __uint_as_float(xd.x & 0xffff0000u);
        float d2 = m[2] - __uint_as_float(xd.y << 16);
        float d3 = m[3] - __uint_as_float(xd.y & 0xffff0000u);
        float d4 = m[4] - __uint_as_float(xd.z << 16);
        float d5 = m[5] - __uint_as_float(xd.z & 0xffff0000u);
        float d6 = m[6] - __uint_as_float(xd.w << 16);
        float d7 = m[7] - __uint_as_float(xd.w & 0xffff0000u);
        r.x = pack2bf(d0, d1);
        r.y = pack2bf(d2, d3);
        r.z = pack2bf(d4, d5);
        r.w = pack2bf(d6, d7);
    }
    if (node < NN)
        *(uint4*)(outu + (size_t)node * 128 + 64 + q * 16 + j * 4) = r;
}

// ---------------- GEMM: 32-row tiles, A preloaded to regs, then MFMA ---------
// A = [xb planes | amx in out second half]. Barrier after A-preload: C writes
// overwrite the amx region other waves read.

__global__ __launch_bounds__(256) void gemm_k(const unsigned* __restrict__ xb,
                                              const unsigned* __restrict__ amxu,
                                              const short* __restrict__ wt,
                                              const float* __restrict__ bias,
                                              float* __restrict__ out) {
    int t = threadIdx.x;
    int w = t >> 6, lane = t & 63;
    int mm = lane & 15, g = lane >> 4;
    int rt = w & 1, ch = w >> 1;
    int nbase = blockIdx.x * 32;
    int r0 = nbase + rt * 16;
    int row = r0 + mm;
    bool rowok = row < NN;

    uint4 afr[8];
#pragma unroll
    for (int kc = 0; kc < 4; kc++)
        afr[kc] = rowok ? *(const uint4*)(xb + (size_t)kc * (NN * 16) + (size_t)row * 16 + g * 4)
                        : make_uint4(0u, 0u, 0u, 0u);
#pragma unroll
    for (int kc = 4; kc < 8; kc++)
        afr[kc] = rowok ? *(const uint4*)(amxu + (size_t)row * 128 + 64 + (kc - 4) * 16 + g * 4)
                        : make_uint4(0u, 0u, 0u, 0u);

    __syncthreads();   // all A reads (incl. amx region of out) before C writes

    f32x4 acc[4];
#pragma unroll
    for (int ct = 0; ct < 4; ct++) {
        float bv = bias[ch * 64 + ct * 16 + mm];
        acc[ct] = (f32x4){bv, bv, bv, bv};
    }

#pragma unroll
    for (int kc = 0; kc < 8; kc++) {
        short8 a;
        __builtin_memcpy(&a, &afr[kc], 16);
#pragma unroll
        for (int ct = 0; ct < 4; ct++) {
            short8 b = *(const short8*)(wt + (size_t)(ch * 64 + ct * 16 + mm) * 256 + kc * 32 + g * 8);
            acc[ct] = __builtin_amdgcn_mfma_f32_16x16x32_bf16(a, b, acc[ct], 0, 0, 0);
        }
    }

#pragma unroll
    for (int ct = 0; ct < 4; ct++) {
#pragma unroll
        for (int i = 0; i < 4; i++) {
            int rr = r0 + g * 4 + i;
            if (rr < NN) out[(size_t)rr * 128 + ch * 64 + ct * 16 + mm] = acc[ct][i];
        }
    }
}

// ---------------- launch ----------------

extern "C" void kernel_launch(void* const* d_in, const int* in_sizes, int n_in,
                              void* d_out, int out_size, void* d_ws, size_t ws_size,
                              hipStream_t stream) {
    const float* x = (const float*)d_in[0];
    const int* ei = (const int*)d_in[1];     // (2, E): [0..E)=src, [E..2E)=dst
    const float* W = (const float*)d_in[2];  // (256, 128) row-major
    const float* bias = (const float*)d_in[3];
    float* out = (float*)d_out;

    // Workspace layout (ints). Total = 4,881,936 ints = 19.53 MB.
    int* wsi = (int*)d_ws;
    int* cnt = wsi;                                          // NN*16+16 ints (64B/dst; cnt[NN*16]=ovc)
    unsigned short* bkt = (unsigned short*)(wsi + 800016);   // NN*32 ush = 800,000 ints (64B-aligned rows)
    unsigned* xb = (unsigned*)(wsi + 1600016);               // 4 planes x 800,000 uints (16B-aligned)
    unsigned short* wt = (unsigned short*)(wsi + 4800016);   // 32768 ush = 16384 ints
    unsigned* ovl = (unsigned*)(wsi + 4816400);              // 65536 uints

    (void)hipMemsetAsync(cnt, 0, 800032 * sizeof(int), stream);  // cnt = 0, ovc = 0

    prep_k<<<8 * SB, 256, 0, stream>>>(ei, x, W, cnt, bkt, ovl, xb, wt);
    gather_k<<<6256, 128, 0, stream>>>(xb, cnt, bkt, ovl, (unsigned*)out);
    gemm_k<<<(NN + 31) / 32, 256, 0, stream>>>(xb, (const unsigned*)out, (const short*)wt,
                                               bias, out);
}